// Round 14
// baseline (184.759 us; speedup 1.0000x reference)
//
#include <hip/hip_runtime.h>
#include <hip/hip_bf16.h>

#define DEV __device__ __forceinline__

typedef unsigned short u16;
typedef unsigned int u32;
typedef __attribute__((ext_vector_type(4))) float f32x4;
typedef __attribute__((ext_vector_type(16))) float f32x16;
typedef __attribute__((ext_vector_type(8))) __bf16 bf16x8;
typedef __attribute__((ext_vector_type(8))) u16 u16x8;
typedef __attribute__((ext_vector_type(4))) u16 u16x4;
typedef __attribute__((ext_vector_type(4))) u32 u32x4;

// 0.125 * log2(e): folded into Wq/bq so S comes out of QK^T pre-scaled for exp2
#define CSCALE 0.18033688011112042f

DEV u16 f2bf(float f) {
    u32 u = __builtin_bit_cast(u32, f);
    u32 r = (u + 0x7fffu + ((u >> 16) & 1u)) >> 16;
    return (u16)r;
}

DEV u16 f2bf_fast(float f) {
    u32 u = __builtin_bit_cast(u32, f);
    return (u16)((u + 0x8000u) >> 16);
}

DEV float fastrcp(float x) {
#if __has_builtin(__builtin_amdgcn_rcpf)
    return __builtin_amdgcn_rcpf(x);
#else
    return 1.0f / x;
#endif
}

DEV u32 cvtpk_bf16(float lo, float hi) {
    u32 r;
    asm("v_cvt_pk_bf16_f32 %0, %1, %2" : "=v"(r) : "v"(lo), "v"(hi));
    return r;
}

DEV void plswap(u32& a, u32& b) {
    asm volatile("v_permlane32_swap_b32 %0, %1" : "+v"(a), "+v"(b));
}

DEV void gload_lds16(const void* g, void* l) {
    void* gg = const_cast<void*>(g);
    __builtin_amdgcn_global_load_lds(
        (const __attribute__((address_space(1))) void*)gg,
        (__attribute__((address_space(3))) void*)l,
        16, 0, 0);
}

DEV f32x16 mfma32(bf16x8 a, bf16x8 b, f32x16 c) {
    return __builtin_amdgcn_mfma_f32_32x32x16_bf16(a, b, c, 0, 0, 0);
}

// ---------------- f32 -> bf16 conversion (optional scale) ----------------
__global__ void cvt_f32_bf16(const float* __restrict__ in, u16* __restrict__ out,
                             int n4, float scale) {
    int i = blockIdx.x * blockDim.x + threadIdx.x;
    if (i < n4) {
        float4 v = ((const float4*)in)[i];
        u16x4 o;
        o[0] = f2bf(v.x * scale); o[1] = f2bf(v.y * scale);
        o[2] = f2bf(v.z * scale); o[3] = f2bf(v.w * scale);
        ((u16x4*)out)[i] = o;
    }
}

// ---------------- concat bias [bq*C | bk | bv] -> f32[3072] ----------------
__global__ void build_bias(const float* __restrict__ bq, const float* __restrict__ bk,
                           const float* __restrict__ bv, float* __restrict__ o) {
    int i = blockIdx.x * blockDim.x + threadIdx.x;
    if (i < 3072) {
        float v;
        if (i < 1024) v = bq[i] * CSCALE;
        else if (i < 2048) v = bk[i - 1024];
        else v = bv[i - 2048];
        o[i] = v;
    }
}

// ---------------- GEMM v1 (R11, proven): 128x128 tile, 4 waves ------------
template<int F32OUT>
__global__ __launch_bounds__(256) void gemm_bt(
    const u16* __restrict__ A, const u16* __restrict__ B,
    const float* __restrict__ bias, void* __restrict__ Cv,
    int K, int ldc, int bnPerXcd)
{
    __shared__ u16 As[128 * 64];
    __shared__ u16 Bs[128 * 64];
    const int t = threadIdx.x;
    const int lane = t & 63;
    const int w = t >> 6;
    const int wm = w >> 1, wn = w & 1;
    const int id = (int)blockIdx.x;
    const int xcd = id & 7, r = id >> 3;
    const int bm = (r / bnPerXcd) * 128;
    const int bn = (xcd * bnPerXcd + r % bnPerXcd) * 128;
    const int lr = lane & 15;
    const int lg = lane >> 4;
    const int swz = (lr & 7) << 4;

    f32x4 acc[4][4] = {};

    for (int k0 = 0; k0 < K; k0 += 64) {
        #pragma unroll
        for (int i = 0; i < 4; ++i) {
            int idx = t + i * 256;
            int row = idx >> 3;
            int gsrc = (idx & 7) ^ (row & 7);
            gload_lds16((const char*)A + ((size_t)(bm + row) * K + k0 + gsrc * 8) * 2,
                        (char*)As + idx * 16);
            gload_lds16((const char*)B + ((size_t)(bn + row) * K + k0 + gsrc * 8) * 2,
                        (char*)Bs + idx * 16);
        }
        __syncthreads();
        #pragma unroll
        for (int kk = 0; kk < 2; ++kk) {
            bf16x8 af[4], bfr[4];
            #pragma unroll
            for (int m = 0; m < 4; ++m)
                af[m] = *(const bf16x8*)((const char*)As + (wm * 64 + m * 16 + lr) * 128 +
                                         ((kk * 64 + lg * 16) ^ swz));
            #pragma unroll
            for (int n = 0; n < 4; ++n)
                bfr[n] = *(const bf16x8*)((const char*)Bs + (wn * 64 + n * 16 + lr) * 128 +
                                          ((kk * 64 + lg * 16) ^ swz));
            #pragma unroll
            for (int m = 0; m < 4; ++m)
                #pragma unroll
                for (int n = 0; n < 4; ++n)
                    acc[m][n] = __builtin_amdgcn_mfma_f32_16x16x32_bf16(af[m], bfr[n], acc[m][n], 0, 0, 0);
        }
        __syncthreads();
    }

    #pragma unroll
    for (int n = 0; n < 4; ++n) {
        int col = bn + wn * 64 + n * 16 + lr;
        float bv = bias[col];
        #pragma unroll
        for (int m = 0; m < 4; ++m) {
            int row0 = bm + wm * 64 + m * 16 + lg * 4;
            #pragma unroll
            for (int r2 = 0; r2 < 4; ++r2) {
                float v = acc[m][n][r2] + bv;
                size_t idx = (size_t)(row0 + r2) * ldc + col;
                if (F32OUT) ((float*)Cv)[idx] = v;
                else        ((u16*)Cv)[idx] = f2bf(v);
            }
        }
    }
}

// ---------------- GEMM v4: 256x256, 8 waves, m201 counted-vmcnt stream ----
// Half-slot pipeline: stream B1(kt+1)@p0, B0(kt+2)@p2, {A0,A1}(kt+2)@p3;
// single vmcnt(6) per tile (vmcnt(0) at stream end). Invariant: entering
// tile kt all 4 halves landed; <=3 halves (6 loads) ever in flight.
__global__ __launch_bounds__(512, 2) void gemm_qkv8(
    const u16* __restrict__ A, const u16* __restrict__ B,
    const float* __restrict__ bias, u16* __restrict__ C,
    int K, int ldc, int ncols)
{
    constexpr int HS = 128 * 64;                 // u16 per half-slot (16 KB)
    __shared__ __align__(16) u16 lds[8 * HS];    // 128 KB: A slots 0..3, B slots 4..7
    u16* Asl = lds;
    u16* Bsl = lds + 4 * HS;

    const int t = threadIdx.x;
    const int lane = t & 63, w = t >> 6;
    const int wm = w >> 2, wn = w & 3;           // 2M x 4N waves, per-wave 128x64
    const int lr = lane & 15, lg = lane >> 4;
    const int rsw = (lr & 7) << 4;

    const int id = (int)blockIdx.x;
    const int bm = (id / ncols) * 256;
    const int bn = (id % ncols) * 256;
    const int NT = K >> 6;                       // 16, even

    const u16 *aP0, *aP1, *bP0, *bP1;
    {
        int row0 = t >> 3, g0 = t & 7;
        int row1 = (t + 512) >> 3, g1 = t & 7;   // idx1&7 == t&7
        aP0 = A + (size_t)(bm + row0) * K + (g0 ^ (row0 & 7)) * 8;
        aP1 = A + (size_t)(bm + row1) * K + (g1 ^ (row1 & 7)) * 8;
        bP0 = B + (size_t)(bn + row0) * K + (g0 ^ (row0 & 7)) * 8;
        bP1 = B + (size_t)(bn + row1) * K + (g1 ^ (row1 & 7)) * 8;
    }
    const size_t hstep = (size_t)128 * K;

    auto issueA = [&](int kt, int h) {
        u16* d = Asl + (((kt & 1) << 1) + h) * HS + t * 8;
        size_t off = (size_t)h * hstep + (size_t)kt * 64;
        gload_lds16(aP0 + off, d);
        gload_lds16(aP1 + off, d + 512 * 8);
    };
    auto issueB = [&](int kt, int h) {
        u16* d = Bsl + (((kt & 1) << 1) + h) * HS + t * 8;
        size_t off = (size_t)h * hstep + (size_t)kt * 64;
        gload_lds16(bP0 + off, d);
        gload_lds16(bP1 + off, d + 512 * 8);
    };

    f32x4 acc[8][4] = {};

    // prologue: tile0 complete + tile1 {B0, A0, A1}; wait with 3 halves in flight
    issueA(0, 0); issueB(0, 0); issueA(0, 1); issueB(0, 1);
    issueB(1, 0); issueA(1, 0); issueA(1, 1);
    asm volatile("s_waitcnt vmcnt(6)" ::: "memory");
    __builtin_amdgcn_s_barrier();

    for (int kt0 = 0; kt0 < NT; kt0 += 2) {
        #pragma unroll
        for (int hh = 0; hh < 2; ++hh) {
            const int BUF = hh;
            const int kt = kt0 + hh;
            const char* Ab = (const char*)(Asl + ((BUF << 1) + wm) * HS);
            const char* Bb = (const char*)(Bsl + ((BUF << 1) + (wn >> 1)) * HS);
            const int rb = (wn & 1) * 64;

            bf16x8 af[2][4], bfr[2][2][2];       // af[kk][m]; bfr[nh][kk][n]
            #pragma unroll
            for (int p = 0; p < 4; ++p) {
                const int mh = p >> 1, nh = p & 1;
                // ---- phase ds_reads (register-reused across phases) ----
                if (p == 0) {
                    #pragma unroll
                    for (int kk = 0; kk < 2; ++kk) {
                        #pragma unroll
                        for (int m = 0; m < 4; ++m)
                            af[kk][m] = *(const bf16x8*)(Ab + (m * 16 + lr) * 128 +
                                                         ((kk * 64 + lg * 16) ^ rsw));
                        #pragma unroll
                        for (int n = 0; n < 2; ++n)
                            bfr[0][kk][n] = *(const bf16x8*)(Bb + (rb + n * 16 + lr) * 128 +
                                                             ((kk * 64 + lg * 16) ^ rsw));
                    }
                } else if (p == 1) {
                    #pragma unroll
                    for (int kk = 0; kk < 2; ++kk)
                        #pragma unroll
                        for (int n = 0; n < 2; ++n)
                            bfr[1][kk][n] = *(const bf16x8*)(Bb + (rb + 32 + n * 16 + lr) * 128 +
                                                             ((kk * 64 + lg * 16) ^ rsw));
                } else if (p == 2) {
                    #pragma unroll
                    for (int kk = 0; kk < 2; ++kk)
                        #pragma unroll
                        for (int m = 0; m < 4; ++m)
                            af[kk][m] = *(const bf16x8*)(Ab + (64 + m * 16 + lr) * 128 +
                                                         ((kk * 64 + lg * 16) ^ rsw));
                }
                // ---- stage issues (into slots freed a phase ago) ----
                if (p == 0)      { if (kt + 1 < NT) issueB(kt + 1, 1); }
                else if (p == 2) { if (kt + 2 < NT) issueB(kt + 2, 0); }
                else if (p == 3) { if (kt + 2 < NT) { issueA(kt + 2, 0); issueA(kt + 2, 1); } }

                __builtin_amdgcn_s_barrier();
                __builtin_amdgcn_s_setprio(1);
                #pragma unroll
                for (int kk = 0; kk < 2; ++kk)
                    #pragma unroll
                    for (int m = 0; m < 4; ++m)
                        #pragma unroll
                        for (int n = 0; n < 2; ++n)
                            acc[mh * 4 + m][nh * 2 + n] = __builtin_amdgcn_mfma_f32_16x16x32_bf16(
                                af[kk][m], bfr[nh][kk][n], acc[mh * 4 + m][nh * 2 + n], 0, 0, 0);
                __builtin_amdgcn_s_setprio(0);
                if (p == 3) {
                    if (kt + 2 < NT) asm volatile("s_waitcnt vmcnt(6)" ::: "memory");
                    else             asm volatile("s_waitcnt vmcnt(0)" ::: "memory");
                }
                __builtin_amdgcn_s_barrier();
            }
        }
    }

    // ---- epilogue: per-wave LDS-bounce, coalesced u16x8 stores ----
    const int wcol = bn + wn * 64;
    float bv[4];
    #pragma unroll
    for (int n = 0; n < 4; ++n) bv[n] = bias[wcol + n * 16 + lr];
    u16* ot = lds + w * (64 * 72);
    const int rowR = lane >> 1, segC = (lane & 1) * 32;
    #pragma unroll
    for (int pass = 0; pass < 2; ++pass) {
        if (pass) { asm volatile("s_waitcnt lgkmcnt(0)" ::: "memory"); __builtin_amdgcn_s_barrier(); }
        #pragma unroll
        for (int mm = 0; mm < 4; ++mm)
            #pragma unroll
            for (int n = 0; n < 4; ++n)
                #pragma unroll
                for (int r = 0; r < 4; ++r)
                    ot[(mm * 16 + lg * 4 + r) * 72 + n * 16 + lr] =
                        f2bf(acc[pass * 4 + mm][n][r] + bv[n]);
        asm volatile("s_waitcnt lgkmcnt(0)" ::: "memory");
        #pragma unroll
        for (int half = 0; half < 2; ++half) {
            int row_l = rowR + half * 32;
            int grow = bm + wm * 128 + pass * 64 + row_l;
            const u16* src = ot + row_l * 72 + segC;
            u16* dst = C + (size_t)grow * ldc + wcol + segC;
            #pragma unroll
            for (int s2 = 0; s2 < 4; ++s2)
                *(u16x8*)(dst + s2 * 8) = *(const u16x8*)(src + s2 * 8);
        }
    }
}

// ---------------- causal flash attention, v9 (unchanged) -------------------
__global__ __launch_bounds__(256, 2) void attn_fwd(
    const u16* __restrict__ QKV, u16* __restrict__ Om)
{
    constexpr int T = 2048, LD = 3072, DO = 1024;
    constexpr int PSTR = 72;
    constexpr float NEG = -3.0e38f;

    __shared__ __align__(16) u16 Ks[2][64 * 64];     // XOR-swizzled K rows
    __shared__ __align__(16) u16 Vt[2][64 * PSTR];   // Vt[d][kv]

    const int t = threadIdx.x, lane = t & 63, w = t >> 6;
    const int ql = lane & 31, hi = lane >> 5;

    const int id = (int)blockIdx.x;
    const int slot = id >> 6;
    const int bh = (id & 7) * 8 + ((id >> 3) & 7);
    const int q0 = (15 - slot) * 128;
    const int b = bh >> 4, h = bh & 15;
    const size_t rowbase = (size_t)b * T * LD + h * 64;
    const u16* Qm = QKV + rowbase;
    const u16* Km = QKV + rowbase + 1024;
    const u16* Vm = QKV + rowbase + 2048;
    const int nt = q0 / 64 + 2;                      // even

    const int qg = q0 + w * 32 + ql;
    const int qmax = q0 + w * 32 + 31;

    bf16x8 qf[4];
    {
        const u16* qp = Qm + (size_t)qg * LD + hi * 8;
        #pragma unroll
        for (int s = 0; s < 4; ++s) qf[s] = *(const bf16x8*)(qp + s * 16);
    }

    f32x16 oa[2] = {};
    float lsum = 0.f;

    const int krow = t >> 3, kslot = t & 7;
    const u16* kCur = Km + (size_t)krow * LD + 8 * (kslot ^ (krow & 7));
    const int kv2 = (t & 31) * 2, dd = (t >> 5) * 8;
    const u16* vCur = Vm + (size_t)kv2 * LD + dd;
    u16x8 vva, vvb;

    auto stageK = [&](int buf) {
        u16* dst = (u16*)Ks + buf * 4096 + t * 8;
        gload_lds16(kCur, dst);
        gload_lds16(kCur + 32 * LD, dst + 2048);
        kCur += 64 * LD;
    };
    auto loadV = [&]() {
        vva = *(const u16x8*)vCur;
        vvb = *(const u16x8*)(vCur + LD);
        vCur += 64 * LD;
    };
    auto writeVt = [&](int buf) {
        u32* vd = (u32*)((u16*)Vt + buf * (64 * PSTR) + dd * PSTR + kv2);
        #pragma unroll
        for (int j = 0; j < 8; ++j)
            vd[j * (PSTR / 2)] = (u32)vva[j] | ((u32)vvb[j] << 16);
    };

    stageK(0);
    loadV();
    writeVt(0);

    for (int it0 = 0; it0 < nt; it0 += 2) {
        #pragma unroll
        for (int half = 0; half < 2; ++half) {
            const int BUF = half;
            const int it = it0 + half;
            const int kv0 = it * 64;
            __syncthreads();

            const bool more = (it + 1 < nt);
            if (more) { stageK(BUF ^ 1); loadV(); }

            const bool a0  = kv0 <= qmax;
            const bool a0h = kv0 + 32 <= qmax;

            f32x16 sa[2] = {};
            __builtin_amdgcn_s_setprio(1);
            #pragma unroll
            for (int n = 0; n < 2; ++n) {
                if (!(n ? a0h : a0)) continue;
                const int row = n * 32 + ql;
                const int swz = (row & 7) << 4;
                #pragma unroll
                for (int s = 0; s < 4; ++s) {
                    bf16x8 kf = *(const bf16x8*)((const char*)Ks + BUF * 8192 + row * 128 +
                                                 ((((s << 1) | hi) << 4) ^ swz));
                    sa[n] = mfma32(kf, qf[s], sa[n]);
                }
            }
            __builtin_amdgcn_s_setprio(0);

            u32x4 pw[2][2];
            if (a0) {
                float rs = 0.f;
                #pragma unroll
                for (int n = 0; n < 2; ++n) {
                    if (n == 1 && !a0h) continue;
                    if (kv0 + n * 32 + 31 > q0 + w * 32) {
                        #pragma unroll
                        for (int r = 0; r < 16; ++r) {
                            int kvg = kv0 + n * 32 + (r & 3) + 8 * (r >> 2) + 4 * hi;
                            if (kvg > qg) sa[n][r] = NEG;
                        }
                    }
                    float pv[16];
                    #pragma unroll
                    for (int r = 0; r < 16; ++r)
                        pv[r] = __builtin_exp2f(sa[n][r]);
                    float s8[8];
                    #pragma unroll
                    for (int r = 0; r < 8; ++r) s8[r] = pv[r] + pv[r + 8];
                    rs += ((s8[0] + s8[4]) + (s8[1] + s8[5])) + ((s8[2] + s8[6]) + (s8[3] + s8[7]));
                    #pragma unroll
                    for (int s = 0; s < 2; ++s) {
                        u32 u0 = cvtpk_bf16(pv[8 * s + 0], pv[8 * s + 1]);
                        u32 u1 = cvtpk_bf16(pv[8 * s + 2], pv[8 * s + 3]);
                        u32 u2 = cvtpk_bf16(pv[8 * s + 4], pv[8 * s + 5]);
                        u32 u3 = cvtpk_bf16(pv[8 * s + 6], pv[8 * s + 7]);
                        plswap(u0, u2);
                        plswap(u1, u3);
                        pw[n][s] = u32x4{u0, u1, u2, u3};
                    }
                }
                rs += __shfl_xor(rs, 32);
                lsum += rs;
            }

            __builtin_amdgcn_s_setprio(1);
            #pragma unroll
            for (int dt = 0; dt < 2; ++dt) {
                const int vrow = dt * 32 + ql;
                #pragma unroll
                for (int n = 0; n < 2; ++n) {
                    if (!(n ? a0h : a0)) continue;
                    #pragma unroll
                    for (int s = 0; s < 2; ++s) {
                        bf16x8 vf = *(const bf16x8*)((const u16*)Vt + BUF * (64 * PSTR) +
                                                     vrow * PSTR + n * 32 + s * 16 + hi * 8);
                        oa[dt] = mfma32(vf, __builtin_bit_cast(bf16x8, pw[n][s]), oa[dt]);
                    }
                }
            }
            __builtin_amdgcn_s_setprio(0);

            if (more) writeVt(BUF ^ 1);
        }
    }

    __syncthreads();
    u16* ot = ((u16*)Vt) + w * (32 * PSTR);
    const float inv = fastrcp(lsum);
    #pragma unroll
    for (int dt = 0; dt < 2; ++dt)
        #pragma unroll
        for (int r = 0; r < 16; ++r) {
            int d = dt * 32 + (r & 3) + 8 * (r >> 2) + 4 * hi;
            ot[ql * PSTR + d] = f2bf_fast(oa[dt][r] * inv);
        }
    const int lq = lane >> 1, hv = lane & 1;
    const size_t obase = (size_t)b * T * DO + h * 64;
    const u16* src = ot + lq * PSTR + hv * 32;
    u16* dst = Om + obase + (size_t)(q0 + w * 32 + lq) * DO + hv * 32;
    #pragma unroll
    for (int seg = 0; seg < 4; ++seg)
        *(u16x8*)(dst + seg * 8) = *(const u16x8*)(src + seg * 8);
}

extern "C" void kernel_launch(void* const* d_in, const int* in_sizes, int n_in,
                              void* d_out, int out_size, void* d_ws, size_t ws_size,
                              hipStream_t stream)
{
    const float* x  = (const float*)d_in[0];
    const float* Wq = (const float*)d_in[1];
    const float* bq = (const float*)d_in[2];
    const float* Wk = (const float*)d_in[3];
    const float* bk = (const float*)d_in[4];
    const float* Wv = (const float*)d_in[5];
    const float* bv = (const float*)d_in[6];
    const float* Wo = (const float*)d_in[7];
    const float* bo = (const float*)d_in[8];

    constexpr int T = 2048, D = 1024;
    constexpr size_t MT = (size_t)4 * T;   // 8192 rows

    const size_t NEED = (size_t)74 << 20;
    if (ws_size < NEED) return;

    char* ws = (char*)d_ws;
    u16* xb    = (u16*)(ws);                          // 16 MiB (dead after QKV GEMM)
    u16* Ob    = (u16*)(ws);                          // reuses xb region
    u16* Wqkvb = (u16*)(ws + ((size_t)16 << 20));     // 6 MiB
    u16* Wob   = (u16*)(ws + ((size_t)22 << 20));     // 2 MiB
    u16* QKVb  = (u16*)(ws + ((size_t)24 << 20));     // 48 MiB
    float* bqkv = (float*)(ws + ((size_t)72 << 20));  // 12 KiB

    int nx4 = (int)(MT * D / 4);
    cvt_f32_bf16<<<(nx4 + 255) / 256, 256, 0, stream>>>(x, xb, nx4, 1.0f);
    int nw4 = D * D / 4;
    cvt_f32_bf16<<<(nw4 + 255) / 256, 256, 0, stream>>>(Wq, Wqkvb, nw4, CSCALE);
    cvt_f32_bf16<<<(nw4 + 255) / 256, 256, 0, stream>>>(Wk, Wqkvb + (size_t)D * D, nw4, 1.0f);
    cvt_f32_bf16<<<(nw4 + 255) / 256, 256, 0, stream>>>(Wv, Wqkvb + (size_t)2 * D * D, nw4, 1.0f);
    cvt_f32_bf16<<<(nw4 + 255) / 256, 256, 0, stream>>>(Wo, Wob, nw4, 1.0f);
    build_bias<<<12, 256, 0, stream>>>(bq, bk, bv, bqkv);

    // fused QKV GEMM: [8192,1024] x [3072,1024]^T -> [8192,3072] bf16
    gemm_qkv8<<<dim3(384), 512, 0, stream>>>(xb, Wqkvb, bqkv, QKVb, D, 3072, 12);

    attn_fwd<<<dim3(1024), 256, 0, stream>>>(QKVb, Ob);

    // output projection: [8192,1024] x [1024,1024]^T -> [8192,1024] f32
    gemm_bt<1><<<dim3(512), 256, 0, stream>>>(Ob, Wob, bo, d_out, D, 1024, 1);
}

// Round 15
// 184.252 us; speedup vs baseline: 1.0028x; 1.0028x over previous
//
#include <hip/hip_runtime.h>
#include <hip/hip_bf16.h>

#define DEV __device__ __forceinline__

typedef unsigned short u16;
typedef unsigned int u32;
typedef __attribute__((ext_vector_type(4))) float f32x4;
typedef __attribute__((ext_vector_type(16))) float f32x16;
typedef __attribute__((ext_vector_type(8))) __bf16 bf16x8;
typedef __attribute__((ext_vector_type(8))) u16 u16x8;
typedef __attribute__((ext_vector_type(4))) u16 u16x4;
typedef __attribute__((ext_vector_type(4))) u32 u32x4;

// 0.125 * log2(e): folded into Wq/bq so S comes out of QK^T pre-scaled for exp2
#define CSCALE 0.18033688011112042f

DEV u16 f2bf(float f) {
    u32 u = __builtin_bit_cast(u32, f);
    u32 r = (u + 0x7fffu + ((u >> 16) & 1u)) >> 16;
    return (u16)r;
}

DEV u16 f2bf_fast(float f) {
    u32 u = __builtin_bit_cast(u32, f);
    return (u16)((u + 0x8000u) >> 16);
}

DEV float fastrcp(float x) {
#if __has_builtin(__builtin_amdgcn_rcpf)
    return __builtin_amdgcn_rcpf(x);
#else
    return 1.0f / x;
#endif
}

DEV u32 cvtpk_bf16(float lo, float hi) {
    u32 r;
    asm("v_cvt_pk_bf16_f32 %0, %1, %2" : "=v"(r) : "v"(lo), "v"(hi));
    return r;
}

DEV void plswap(u32& a, u32& b) {
    asm volatile("v_permlane32_swap_b32 %0, %1" : "+v"(a), "+v"(b));
}

DEV void gload_lds16(const void* g, void* l) {
    void* gg = const_cast<void*>(g);
    __builtin_amdgcn_global_load_lds(
        (const __attribute__((address_space(1))) void*)gg,
        (__attribute__((address_space(3))) void*)l,
        16, 0, 0);
}

DEV f32x16 mfma32(bf16x8 a, bf16x8 b, f32x16 c) {
    return __builtin_amdgcn_mfma_f32_32x32x16_bf16(a, b, c, 0, 0, 0);
}

// ---------------- f32 -> bf16 conversion (optional scale) ----------------
__global__ void cvt_f32_bf16(const float* __restrict__ in, u16* __restrict__ out,
                             int n4, float scale) {
    int i = blockIdx.x * blockDim.x + threadIdx.x;
    if (i < n4) {
        float4 v = ((const float4*)in)[i];
        u16x4 o;
        o[0] = f2bf(v.x * scale); o[1] = f2bf(v.y * scale);
        o[2] = f2bf(v.z * scale); o[3] = f2bf(v.w * scale);
        ((u16x4*)out)[i] = o;
    }
}

// ---------------- concat bias [bq*C | bk | bv] -> f32[3072] ----------------
__global__ void build_bias(const float* __restrict__ bq, const float* __restrict__ bk,
                           const float* __restrict__ bv, float* __restrict__ o) {
    int i = blockIdx.x * blockDim.x + threadIdx.x;
    if (i < 3072) {
        float v;
        if (i < 1024) v = bq[i] * CSCALE;
        else if (i < 2048) v = bk[i - 1024];
        else v = bv[i - 2048];
        o[i] = v;
    }
}

// ---------------- GEMM v1 (R11, proven): 128x128 tile, 4 waves ------------
template<int F32OUT>
__global__ __launch_bounds__(256) void gemm_bt(
    const u16* __restrict__ A, const u16* __restrict__ B,
    const float* __restrict__ bias, void* __restrict__ Cv,
    int K, int ldc, int bnPerXcd)
{
    __shared__ u16 As[128 * 64];
    __shared__ u16 Bs[128 * 64];
    const int t = threadIdx.x;
    const int lane = t & 63;
    const int w = t >> 6;
    const int wm = w >> 1, wn = w & 1;
    const int id = (int)blockIdx.x;
    const int xcd = id & 7, r = id >> 3;
    const int bm = (r / bnPerXcd) * 128;
    const int bn = (xcd * bnPerXcd + r % bnPerXcd) * 128;
    const int lr = lane & 15;
    const int lg = lane >> 4;
    const int swz = (lr & 7) << 4;

    f32x4 acc[4][4] = {};

    for (int k0 = 0; k0 < K; k0 += 64) {
        #pragma unroll
        for (int i = 0; i < 4; ++i) {
            int idx = t + i * 256;
            int row = idx >> 3;
            int gsrc = (idx & 7) ^ (row & 7);
            gload_lds16((const char*)A + ((size_t)(bm + row) * K + k0 + gsrc * 8) * 2,
                        (char*)As + idx * 16);
            gload_lds16((const char*)B + ((size_t)(bn + row) * K + k0 + gsrc * 8) * 2,
                        (char*)Bs + idx * 16);
        }
        __syncthreads();
        #pragma unroll
        for (int kk = 0; kk < 2; ++kk) {
            bf16x8 af[4], bfr[4];
            #pragma unroll
            for (int m = 0; m < 4; ++m)
                af[m] = *(const bf16x8*)((const char*)As + (wm * 64 + m * 16 + lr) * 128 +
                                         ((kk * 64 + lg * 16) ^ swz));
            #pragma unroll
            for (int n = 0; n < 4; ++n)
                bfr[n] = *(const bf16x8*)((const char*)Bs + (wn * 64 + n * 16 + lr) * 128 +
                                          ((kk * 64 + lg * 16) ^ swz));
            #pragma unroll
            for (int m = 0; m < 4; ++m)
                #pragma unroll
                for (int n = 0; n < 4; ++n)
                    acc[m][n] = __builtin_amdgcn_mfma_f32_16x16x32_bf16(af[m], bfr[n], acc[m][n], 0, 0, 0);
        }
        __syncthreads();
    }

    #pragma unroll
    for (int n = 0; n < 4; ++n) {
        int col = bn + wn * 64 + n * 16 + lr;
        float bv = bias[col];
        #pragma unroll
        for (int m = 0; m < 4; ++m) {
            int row0 = bm + wm * 64 + m * 16 + lg * 4;
            #pragma unroll
            for (int r2 = 0; r2 < 4; ++r2) {
                float v = acc[m][n][r2] + bv;
                size_t idx = (size_t)(row0 + r2) * ldc + col;
                if (F32OUT) ((float*)Cv)[idx] = v;
                else        ((u16*)Cv)[idx] = f2bf(v);
            }
        }
    }
}

// ---------------- GEMM v4: 256x256, 8 waves, m201 counted-vmcnt stream ----
// Half-slot pipeline: stream B1(kt+1)@p0, B0(kt+2)@p2, {A0,A1}(kt+2)@p3;
// single vmcnt(6) per tile (vmcnt(0) at stream end). Invariant: entering
// tile kt all 4 halves landed; <=3 halves (6 loads) ever in flight.
__global__ __launch_bounds__(512, 2) void gemm_qkv8(
    const u16* __restrict__ A, const u16* __restrict__ B,
    const float* __restrict__ bias, u16* __restrict__ C,
    int K, int ldc, int ncols)
{
    constexpr int HS = 128 * 64;                 // u16 per half-slot (16 KB)
    __shared__ __align__(16) u16 lds[8 * HS];    // 128 KB: A slots 0..3, B slots 4..7
    u16* Asl = lds;
    u16* Bsl = lds + 4 * HS;

    const int t = threadIdx.x;
    const int lane = t & 63, w = t >> 6;
    const int wm = w >> 2, wn = w & 3;           // 2M x 4N waves, per-wave 128x64
    const int lr = lane & 15, lg = lane >> 4;
    const int rsw = (lr & 7) << 4;

    const int id = (int)blockIdx.x;
    const int bm = (id / ncols) * 256;
    const int bn = (id % ncols) * 256;
    const int NT = K >> 6;                       // 16, even

    const u16 *aP0, *aP1, *bP0, *bP1;
    {
        int row0 = t >> 3, g0 = t & 7;
        int row1 = (t + 512) >> 3, g1 = t & 7;   // idx1&7 == t&7
        aP0 = A + (size_t)(bm + row0) * K + (g0 ^ (row0 & 7)) * 8;
        aP1 = A + (size_t)(bm + row1) * K + (g1 ^ (row1 & 7)) * 8;
        bP0 = B + (size_t)(bn + row0) * K + (g0 ^ (row0 & 7)) * 8;
        bP1 = B + (size_t)(bn + row1) * K + (g1 ^ (row1 & 7)) * 8;
    }
    const size_t hstep = (size_t)128 * K;

    auto issueA = [&](int kt, int h) {
        u16* d = Asl + (((kt & 1) << 1) + h) * HS + t * 8;
        size_t off = (size_t)h * hstep + (size_t)kt * 64;
        gload_lds16(aP0 + off, d);
        gload_lds16(aP1 + off, d + 512 * 8);
    };
    auto issueB = [&](int kt, int h) {
        u16* d = Bsl + (((kt & 1) << 1) + h) * HS + t * 8;
        size_t off = (size_t)h * hstep + (size_t)kt * 64;
        gload_lds16(bP0 + off, d);
        gload_lds16(bP1 + off, d + 512 * 8);
    };

    f32x4 acc[8][4] = {};

    // prologue: tile0 complete + tile1 {B0, A0, A1}; wait with 3 halves in flight
    issueA(0, 0); issueB(0, 0); issueA(0, 1); issueB(0, 1);
    issueB(1, 0); issueA(1, 0); issueA(1, 1);
    asm volatile("s_waitcnt vmcnt(6)" ::: "memory");
    __builtin_amdgcn_s_barrier();

    for (int kt0 = 0; kt0 < NT; kt0 += 2) {
        #pragma unroll
        for (int hh = 0; hh < 2; ++hh) {
            const int BUF = hh;
            const int kt = kt0 + hh;
            const char* Ab = (const char*)(Asl + ((BUF << 1) + wm) * HS);
            const char* Bb = (const char*)(Bsl + ((BUF << 1) + (wn >> 1)) * HS);
            const int rb = (wn & 1) * 64;

            bf16x8 af[2][4], bfr[2][2][2];       // af[kk][m]; bfr[nh][kk][n]
            #pragma unroll
            for (int p = 0; p < 4; ++p) {
                const int mh = p >> 1, nh = p & 1;
                // ---- phase ds_reads (register-reused across phases) ----
                if (p == 0) {
                    #pragma unroll
                    for (int kk = 0; kk < 2; ++kk) {
                        #pragma unroll
                        for (int m = 0; m < 4; ++m)
                            af[kk][m] = *(const bf16x8*)(Ab + (m * 16 + lr) * 128 +
                                                         ((kk * 64 + lg * 16) ^ rsw));
                        #pragma unroll
                        for (int n = 0; n < 2; ++n)
                            bfr[0][kk][n] = *(const bf16x8*)(Bb + (rb + n * 16 + lr) * 128 +
                                                             ((kk * 64 + lg * 16) ^ rsw));
                    }
                } else if (p == 1) {
                    #pragma unroll
                    for (int kk = 0; kk < 2; ++kk)
                        #pragma unroll
                        for (int n = 0; n < 2; ++n)
                            bfr[1][kk][n] = *(const bf16x8*)(Bb + (rb + 32 + n * 16 + lr) * 128 +
                                                             ((kk * 64 + lg * 16) ^ rsw));
                } else if (p == 2) {
                    #pragma unroll
                    for (int kk = 0; kk < 2; ++kk)
                        #pragma unroll
                        for (int m = 0; m < 4; ++m)
                            af[kk][m] = *(const bf16x8*)(Ab + (64 + m * 16 + lr) * 128 +
                                                         ((kk * 64 + lg * 16) ^ rsw));
                }
                // ---- stage issues (into slots freed a phase ago) ----
                if (p == 0)      { if (kt + 1 < NT) issueB(kt + 1, 1); }
                else if (p == 2) { if (kt + 2 < NT) issueB(kt + 2, 0); }
                else if (p == 3) { if (kt + 2 < NT) { issueA(kt + 2, 0); issueA(kt + 2, 1); } }

                __builtin_amdgcn_s_barrier();
                __builtin_amdgcn_s_setprio(1);
                #pragma unroll
                for (int kk = 0; kk < 2; ++kk)
                    #pragma unroll
                    for (int m = 0; m < 4; ++m)
                        #pragma unroll
                        for (int n = 0; n < 2; ++n)
                            acc[mh * 4 + m][nh * 2 + n] = __builtin_amdgcn_mfma_f32_16x16x32_bf16(
                                af[kk][m], bfr[nh][kk][n], acc[mh * 4 + m][nh * 2 + n], 0, 0, 0);
                __builtin_amdgcn_s_setprio(0);
                if (p == 3) {
                    if (kt + 2 < NT) asm volatile("s_waitcnt vmcnt(6)" ::: "memory");
                    else             asm volatile("s_waitcnt vmcnt(0)" ::: "memory");
                }
                __builtin_amdgcn_s_barrier();
            }
        }
    }

    // ---- epilogue: per-wave LDS-bounce, coalesced u16x8 stores ----
    const int wcol = bn + wn * 64;
    float bv[4];
    #pragma unroll
    for (int n = 0; n < 4; ++n) bv[n] = bias[wcol + n * 16 + lr];
    u16* ot = lds + w * (64 * 72);
    const int rowR = lane >> 1, segC = (lane & 1) * 32;
    #pragma unroll
    for (int pass = 0; pass < 2; ++pass) {
        if (pass) { asm volatile("s_waitcnt lgkmcnt(0)" ::: "memory"); __builtin_amdgcn_s_barrier(); }
        #pragma unroll
        for (int mm = 0; mm < 4; ++mm)
            #pragma unroll
            for (int n = 0; n < 4; ++n)
                #pragma unroll
                for (int r = 0; r < 4; ++r)
                    ot[(mm * 16 + lg * 4 + r) * 72 + n * 16 + lr] =
                        f2bf(acc[pass * 4 + mm][n][r] + bv[n]);
        asm volatile("s_waitcnt lgkmcnt(0)" ::: "memory");
        #pragma unroll
        for (int half = 0; half < 2; ++half) {
            int row_l = rowR + half * 32;
            int grow = bm + wm * 128 + pass * 64 + row_l;
            const u16* src = ot + row_l * 72 + segC;
            u16* dst = C + (size_t)grow * ldc + wcol + segC;
            #pragma unroll
            for (int s2 = 0; s2 < 4; ++s2)
                *(u16x8*)(dst + s2 * 8) = *(const u16x8*)(src + s2 * 8);
        }
    }
}

// ---------------- causal flash attention, v9 (unchanged) -------------------
__global__ __launch_bounds__(256, 2) void attn_fwd(
    const u16* __restrict__ QKV, u16* __restrict__ Om)
{
    constexpr int T = 2048, LD = 3072, DO = 1024;
    constexpr int PSTR = 72;
    constexpr float NEG = -3.0e38f;

    __shared__ __align__(16) u16 Ks[2][64 * 64];     // XOR-swizzled K rows
    __shared__ __align__(16) u16 Vt[2][64 * PSTR];   // Vt[d][kv]

    const int t = threadIdx.x, lane = t & 63, w = t >> 6;
    const int ql = lane & 31, hi = lane >> 5;

    const int id = (int)blockIdx.x;
    const int slot = id >> 6;
    const int bh = (id & 7) * 8 + ((id >> 3) & 7);
    const int q0 = (15 - slot) * 128;
    const int b = bh >> 4, h = bh & 15;
    const size_t rowbase = (size_t)b * T * LD + h * 64;
    const u16* Qm = QKV + rowbase;
    const u16* Km = QKV + rowbase + 1024;
    const u16* Vm = QKV + rowbase + 2048;
    const int nt = q0 / 64 + 2;                      // even

    const int qg = q0 + w * 32 + ql;
    const int qmax = q0 + w * 32 + 31;

    bf16x8 qf[4];
    {
        const u16* qp = Qm + (size_t)qg * LD + hi * 8;
        #pragma unroll
        for (int s = 0; s < 4; ++s) qf[s] = *(const bf16x8*)(qp + s * 16);
    }

    f32x16 oa[2] = {};
    float lsum = 0.f;

    const int krow = t >> 3, kslot = t & 7;
    const u16* kCur = Km + (size_t)krow * LD + 8 * (kslot ^ (krow & 7));
    const int kv2 = (t & 31) * 2, dd = (t >> 5) * 8;
    const u16* vCur = Vm + (size_t)kv2 * LD + dd;
    u16x8 vva, vvb;

    auto stageK = [&](int buf) {
        u16* dst = (u16*)Ks + buf * 4096 + t * 8;
        gload_lds16(kCur, dst);
        gload_lds16(kCur + 32 * LD, dst + 2048);
        kCur += 64 * LD;
    };
    auto loadV = [&]() {
        vva = *(const u16x8*)vCur;
        vvb = *(const u16x8*)(vCur + LD);
        vCur += 64 * LD;
    };
    auto writeVt = [&](int buf) {
        u32* vd = (u32*)((u16*)Vt + buf * (64 * PSTR) + dd * PSTR + kv2);
        #pragma unroll
        for (int j = 0; j < 8; ++j)
            vd[j * (PSTR / 2)] = (u32)vva[j] | ((u32)vvb[j] << 16);
    };

    stageK(0);
    loadV();
    writeVt(0);

    for (int it0 = 0; it0 < nt; it0 += 2) {
        #pragma unroll
        for (int half = 0; half < 2; ++half) {
            const int BUF = half;
            const int it = it0 + half;
            const int kv0 = it * 64;
            __syncthreads();

            const bool more = (it + 1 < nt);
            if (more) { stageK(BUF ^ 1); loadV(); }

            const bool a0  = kv0 <= qmax;
            const bool a0h = kv0 + 32 <= qmax;

            f32x16 sa[2] = {};
            __builtin_amdgcn_s_setprio(1);
            #pragma unroll
            for (int n = 0; n < 2; ++n) {
                if (!(n ? a0h : a0)) continue;
                const int row = n * 32 + ql;
                const int swz = (row & 7) << 4;
                #pragma unroll
                for (int s = 0; s < 4; ++s) {
                    bf16x8 kf = *(const bf16x8*)((const char*)Ks + BUF * 8192 + row * 128 +
                                                 ((((s << 1) | hi) << 4) ^ swz));
                    sa[n] = mfma32(kf, qf[s], sa[n]);
                }
            }
            __builtin_amdgcn_s_setprio(0);

            u32x4 pw[2][2];
            if (a0) {
                float rs = 0.f;
                #pragma unroll
                for (int n = 0; n < 2; ++n) {
                    if (n == 1 && !a0h) continue;
                    if (kv0 + n * 32 + 31 > q0 + w * 32) {
                        #pragma unroll
                        for (int r = 0; r < 16; ++r) {
                            int kvg = kv0 + n * 32 + (r & 3) + 8 * (r >> 2) + 4 * hi;
                            if (kvg > qg) sa[n][r] = NEG;
                        }
                    }
                    float pv[16];
                    #pragma unroll
                    for (int r = 0; r < 16; ++r)
                        pv[r] = __builtin_exp2f(sa[n][r]);
                    float s8[8];
                    #pragma unroll
                    for (int r = 0; r < 8; ++r) s8[r] = pv[r] + pv[r + 8];
                    rs += ((s8[0] + s8[4]) + (s8[1] + s8[5])) + ((s8[2] + s8[6]) + (s8[3] + s8[7]));
                    #pragma unroll
                    for (int s = 0; s < 2; ++s) {
                        u32 u0 = cvtpk_bf16(pv[8 * s + 0], pv[8 * s + 1]);
                        u32 u1 = cvtpk_bf16(pv[8 * s + 2], pv[8 * s + 3]);
                        u32 u2 = cvtpk_bf16(pv[8 * s + 4], pv[8 * s + 5]);
                        u32 u3 = cvtpk_bf16(pv[8 * s + 6], pv[8 * s + 7]);
                        plswap(u0, u2);
                        plswap(u1, u3);
                        pw[n][s] = u32x4{u0, u1, u2, u3};
                    }
                }
                rs += __shfl_xor(rs, 32);
                lsum += rs;
            }

            __builtin_amdgcn_s_setprio(1);
            #pragma unroll
            for (int dt = 0; dt < 2; ++dt) {
                const int vrow = dt * 32 + ql;
                #pragma unroll
                for (int n = 0; n < 2; ++n) {
                    if (!(n ? a0h : a0)) continue;
                    #pragma unroll
                    for (int s = 0; s < 2; ++s) {
                        bf16x8 vf = *(const bf16x8*)((const u16*)Vt + BUF * (64 * PSTR) +
                                                     vrow * PSTR + n * 32 + s * 16 + hi * 8);
                        oa[dt] = mfma32(vf, __builtin_bit_cast(bf16x8, pw[n][s]), oa[dt]);
                    }
                }
            }
            __builtin_amdgcn_s_setprio(0);

            if (more) writeVt(BUF ^ 1);
        }
    }

    __syncthreads();
    u16* ot = ((u16*)Vt) + w * (32 * PSTR);
    const float inv = fastrcp(lsum);
    #pragma unroll
    for (int dt = 0; dt < 2; ++dt)
        #pragma unroll
        for (int r = 0; r < 16; ++r) {
            int d = dt * 32 + (r & 3) + 8 * (r >> 2) + 4 * hi;
            ot[ql * PSTR + d] = f2bf_fast(oa[dt][r] * inv);
        }
    const int lq = lane >> 1, hv = lane & 1;
    const size_t obase = (size_t)b * T * DO + h * 64;
    const u16* src = ot + lq * PSTR + hv * 32;
    u16* dst = Om + obase + (size_t)(q0 + w * 32 + lq) * DO + hv * 32;
    #pragma unroll
    for (int seg = 0; seg < 4; ++seg)
        *(u16x8*)(dst + seg * 8) = *(const u16x8*)(src + seg * 8);
}

extern "C" void kernel_launch(void* const* d_in, const int* in_sizes, int n_in,
                              void* d_out, int out_size, void* d_ws, size_t ws_size,
                              hipStream_t stream)
{
    const float* x  = (const float*)d_in[0];
    const float* Wq = (const float*)d_in[1];
    const float* bq = (const float*)d_in[2];
    const float* Wk = (const float*)d_in[3];
    const float* bk = (const float*)d_in[4];
    const float* Wv = (const float*)d_in[5];
    const float* bv = (const float*)d_in[6];
    const float* Wo = (const float*)d_in[7];
    const float* bo = (const float*)d_in[8];

    constexpr int T = 2048, D = 1024;
    constexpr size_t MT = (size_t)4 * T;   // 8192 rows

    const size_t NEED = (size_t)74 << 20;
    if (ws_size < NEED) return;

    char* ws = (char*)d_ws;
    u16* xb    = (u16*)(ws);                          // 16 MiB (dead after QKV GEMM)
    u16* Ob    = (u16*)(ws);                          // reuses xb region
    u16* Wqkvb = (u16*)(ws + ((size_t)16 << 20));     // 6 MiB
    u16* Wob   = (u16*)(ws + ((size_t)22 << 20));     // 2 MiB
    u16* QKVb  = (u16*)(ws + ((size_t)24 << 20));     // 48 MiB
    float* bqkv = (float*)(ws + ((size_t)72 << 20));  // 12 KiB

    int nx4 = (int)(MT * D / 4);
    cvt_f32_bf16<<<(nx4 + 255) / 256, 256, 0, stream>>>(x, xb, nx4, 1.0f);
    int nw4 = D * D / 4;
    cvt_f32_bf16<<<(nw4 + 255) / 256, 256, 0, stream>>>(Wq, Wqkvb, nw4, CSCALE);
    cvt_f32_bf16<<<(nw4 + 255) / 256, 256, 0, stream>>>(Wk, Wqkvb + (size_t)D * D, nw4, 1.0f);
    cvt_f32_bf16<<<(nw4 + 255) / 256, 256, 0, stream>>>(Wv, Wqkvb + (size_t)2 * D * D, nw4, 1.0f);
    cvt_f32_bf16<<<(nw4 + 255) / 256, 256, 0, stream>>>(Wo, Wob, nw4, 1.0f);
    build_bias<<<12, 256, 0, stream>>>(bq, bk, bv, bqkv);

    // fused QKV GEMM: [8192,1024] x [3072,1024]^T -> [8192,3072] bf16
    gemm_qkv8<<<dim3(384), 512, 0, stream>>>(xb, Wqkvb, bqkv, QKVb, D, 3072, 12);

    attn_fwd<<<dim3(1024), 256, 0, stream>>>(QKVb, Ob);

    // output projection: [8192,1024] x [1024,1024]^T -> [8192,1024] f32
    gemm_bt<1><<<dim3(512), 256, 0, stream>>>(Ob, Wob, bo, d_out, D, 1024, 1);
}